// Round 2
// baseline (212.008 us; speedup 1.0000x reference)
//
#include <hip/hip_runtime.h>
#include <hip/hip_bf16.h>
#include <math.h>

// Problem: out[b, :] = z[b, :] @ W[c_b*12288 : (c_b+1)*12288, :]^T + bias[c_b block]
//   z: (512, 128) f32,  W: (196608, 128) f32,  bias: (196608,) f32
//   c_b = mod(floor(|np.sum(z[b], f32-pairwise)| * 1000), 16)   <-- f32 exact order!
//   out: (512, 12288) f32
//
// Strategy: group samples by bucket so each W block is read from HBM once
// (~100.7 MB W + 25.2 MB out => ~20 us memory floor). f32 vector FMA
// (1.61 GFLOP ~ 10 us) — memory bound. z broadcast via wave-uniform loads.
//
// Hash MUST replicate numpy's pairwise_sum for n=128 (the n<=PW_BLOCKSIZE
// branch): 8 stride-8 f32 accumulators combined ((r0+r1)+(r2+r3))+((r4+r5)+(r6+r7)).
// An f64 sum mispicks ~1% of samples at the floor(|s|*1000) boundaries
// (round-1 failure: absmax 5.9 = one full wrong output block).

#define N_LINEARS 16
#define ZD 128
#define BATCH 512
#define BLOCK_OUT 12288          // 3*64*64 outputs per linear
#define SCHUNK 32                // sample accumulators per thread
#define TJ 256                   // output columns per block (= threads)

// ---------------- Kernel A: hash + bucket lists ----------------
// 1 block, 512 threads = 1 thread per sample; numpy-exact f32 pairwise sum.
__global__ __launch_bounds__(512) void hash_kernel(
    const float* __restrict__ z, int* __restrict__ counts, int* __restrict__ lists) {
  __shared__ int cnt[N_LINEARS];
  const int tid = threadIdx.x;
  if (tid < N_LINEARS) cnt[tid] = 0;
  __syncthreads();

  const int b = tid;             // sample 0..511
  const float* zr = z + b * ZD;

  // numpy pairwise_sum, n=128 <= PW_BLOCKSIZE: 8 stride-8 accumulators.
  float r[8];
  #pragma unroll
  for (int j = 0; j < 8; ++j) r[j] = zr[j];
  for (int i = 8; i < ZD; i += 8) {
    #pragma unroll
    for (int j = 0; j < 8; ++j) r[j] += zr[i + j];
  }
  float res = ((r[0] + r[1]) + (r[2] + r[3])) + ((r[4] + r[5]) + (r[6] + r[7]));

  float v = fabsf(res) * 1000.0f;          // f32, matches np float32 * 1000.0
  int cb = ((int)floorf(v)) & (N_LINEARS - 1);
  int pos = atomicAdd(&cnt[cb], 1);
  lists[(cb << 9) + pos] = b;

  __syncthreads();
  if (tid < N_LINEARS) counts[tid] = cnt[tid];
}

// ---------------- Kernel B: grouped GEMM ----------------
// grid = (48 j-tiles, 16 buckets), 256 threads. Thread owns one column j.
// W row streamed in 32-float register chunks (HBM read once per pass);
// z read via wave-uniform (scalar) loads; 32 sample accumulators.
__global__ __launch_bounds__(TJ) void gen_main_kernel(
    const float* __restrict__ z, const float* __restrict__ W,
    const float* __restrict__ bias, float* __restrict__ out,
    const int* __restrict__ counts, const int* __restrict__ lists) {
  const int c = blockIdx.y;
  const int j = blockIdx.x * TJ + threadIdx.x;       // 0..12287
  const int n = counts[c];
  if (n == 0) return;
  const int* lst = lists + (c << 9);

  const size_t row = (size_t)c * BLOCK_OUT + (size_t)j;
  const float4* __restrict__ Wv = (const float4*)(W + row * ZD);
  const float bj = bias[row];

  for (int s0 = 0; s0 < n; s0 += SCHUNK) {
    const int m = n - s0;                            // samples left (guard with si<m)
    float acc[SCHUNK];
    #pragma unroll
    for (int si = 0; si < SCHUNK; ++si) acc[si] = bj;

    for (int kc = 0; kc < 4; ++kc) {                 // 4 chunks of 32 k-values
      float4 w[8];
      #pragma unroll
      for (int i = 0; i < 8; ++i) w[i] = Wv[kc * 8 + i];

      #pragma unroll
      for (int si = 0; si < SCHUNK; ++si) {
        if (si < m) {
          const int bs = __builtin_amdgcn_readfirstlane(lst[s0 + si]);
          const float* __restrict__ zr = z + (size_t)bs * ZD + kc * 32;
          float a = acc[si];
          #pragma unroll
          for (int i = 0; i < 8; ++i) {
            a = fmaf(w[i].x, zr[i * 4 + 0], a);
            a = fmaf(w[i].y, zr[i * 4 + 1], a);
            a = fmaf(w[i].z, zr[i * 4 + 2], a);
            a = fmaf(w[i].w, zr[i * 4 + 3], a);
          }
          acc[si] = a;
        }
      }
    }

    #pragma unroll
    for (int si = 0; si < SCHUNK; ++si) {
      if (si < m) {
        const int bs = __builtin_amdgcn_readfirstlane(lst[s0 + si]);
        out[(size_t)bs * BLOCK_OUT + (size_t)j] = acc[si];
      }
    }
  }
}

extern "C" void kernel_launch(void* const* d_in, const int* in_sizes, int n_in,
                              void* d_out, int out_size, void* d_ws, size_t ws_size,
                              hipStream_t stream) {
  const float* z    = (const float*)d_in[0];   // 512*128
  const float* W    = (const float*)d_in[1];   // 196608*128
  const float* bias = (const float*)d_in[2];   // 196608
  float* out = (float*)d_out;                  // 512*12288

  int* counts = (int*)d_ws;                    // 16 ints
  int* lists  = counts + N_LINEARS;            // 16*512 ints

  hipLaunchKernelGGL(hash_kernel, dim3(1), dim3(512), 0, stream, z, counts, lists);

  dim3 grid(BLOCK_OUT / TJ, N_LINEARS);        // (48, 16)
  hipLaunchKernelGGL(gen_main_kernel, grid, dim3(TJ), 0, stream,
                     z, W, bias, out, counts, lists);
}